// Round 20
// baseline (291.977 us; speedup 1.0000x reference)
//
#include <hip/hip_runtime.h>
#include <hip/hip_cooperative_groups.h>
#include <cstdint>
#include <cstddef>

namespace cg = cooperative_groups;

typedef unsigned long long u64;
typedef unsigned int u32;
typedef unsigned short u16;
typedef unsigned char u8;

#define R_ANCH 96000
#define R4     24000 // R_ANCH / 4 (float4 units)
#define NIMG   8
#define KMIX   5
#define PRE    2000
#define POST   1000
#define NGT    32
#define NCHUNK 375   // R_ANCH / 256 (label/loss kernels)
#define ACHUNK 94    // ceil(R4 / 256) — kA main blocks (4 anchors/thread)
#define NBLK   48    // blocks per image for parallel scan kernels
#define MROW   2048  // maskLT row stride (padded PRE)
#define SCAP   16    // per-row suppressor-list capacity (overflow -> dense path)
#define BIG_TH 64    // kRank: bins larger than this get level-1 split
#define CAP_BIN 6144 // refinement trigger: crossing-bin count above this -> refine
#define CAND_CAP 8192// global/LDS candidate capacity (PRE-1 + CAP_BIN = 8143 max)
#define GC_STRIDE 16 // gcnt padding: 64 B per image
#define RPART  32    // kRank partitions per image (replicated-state parallelism)

#define IMG_SZ        1280.0f
#define NMS_T         0.7f
#define SCALE_CLAMP_F 4.135166556742356f
#define HALF_L2PI     0.9189385332046727f

__device__ __forceinline__ u64 make_key(float s, int r) {
  u32 u = __float_as_uint(s);
  u = (u & 0x80000000u) ? ~u : (u | 0x80000000u);
  return ((u64)u << 32) | (u64)(0xFFFFFFFFu - (u32)r);
}

__device__ __forceinline__ float dec_score(u64 key) {
  u32 o = (u32)(key >> 32);
  u32 bits = (o & 0x80000000u) ? (o ^ 0x80000000u) : ~o;
  return __uint_as_float(bits);
}

// EXACT-PATH IoU (NMS only): must match reference bit-for-bit since NMS
// decisions select whole boxes. Label-path code uses division-free
// cross-multiplied compares (loss-only, high tolerance).
__device__ __forceinline__ float iou_pair(float a0,float a1,float a2,float a3,
                                          float b0,float b1,float b2,float b3) {
#pragma clang fp contract(off)
  float areaA = (a2-a0)*(a3-a1);
  float areaB = (b2-b0)*(b3-b1);
  float lx=fmaxf(a0,b0), ly=fmaxf(a1,b1);
  float rx=fminf(a2,b2), ry=fminf(a3,b3);
  float iw=fmaxf(rx-lx,0.0f), ih=fmaxf(ry-ly,0.0f);
  float inter=iw*ih;
  return inter / fmaxf(areaA+areaB-inter, 1e-9f);
}

// pick: from a 2048-bin histogram (bin d high = higher keys), find the bin
// containing the k-th largest key. 256 threads. s_i >= 8 ints, s_u >= 3 u32.
__device__ __forceinline__ void pick2048(const u32* __restrict__ hist, int k,
                                         int* s_i, u32* s_u,
                                         int& d_out, int& k_out, u32& cnt_out) {
  int tid = threadIdx.x;
  int lane = tid & 63, w = tid >> 6;
  u32 h[8]; u32 ssum = 0;
#pragma unroll
  for (int i=0;i<8;++i){ h[i] = hist[2047 - (tid*8 + i)]; ssum += h[i]; }
  u32 incl = ssum;
  for (int off=1; off<64; off<<=1){
    u32 t = (u32)__shfl_up((int)incl, off, 64);
    if (lane >= off) incl += t;
  }
  if (lane==63) s_i[w] = (int)incl;
  __syncthreads();
  u32 base = 0;
  for (int ww=0; ww<w; ++ww) base += (u32)s_i[ww];
  u32 run = base + incl - ssum;              // exclusive prefix (descending keys)
#pragma unroll
  for (int i=0;i<8;++i){
    u32 nr = run + h[i];
    if (run < (u32)k && nr >= (u32)k){       // unique crossing thread
      s_u[0] = (u32)(2047 - (tid*8+i));
      s_u[1] = (u32)k - run;
      s_u[2] = h[i];
    }
    run = nr;
  }
  __syncthreads();
  d_out = (int)s_u[0]; k_out = (int)s_u[1]; cnt_out = s_u[2];
  __syncthreads();
}

// descending exclusive prefix over 2048 bins, 1024 threads (2 bins/thread).
// Caller must __syncthreads() before (h ready) and after (off ready).
__device__ __forceinline__ void scan2048_desc(const u32* __restrict__ h,
                                              u32* __restrict__ off,
                                              u32* __restrict__ wsum, int tid) {
  int b_hi = 2047 - 2*tid, b_lo = b_hi - 1;
  u32 h_hi = h[b_hi], h_lo = h[b_lo];
  u32 sum = h_hi + h_lo;
  u32 incl = sum;
  int lane = tid & 63, wv = tid >> 6;
  for (int o=1; o<64; o<<=1){
    u32 t = (u32)__shfl_up((int)incl, o, 64);
    if (lane >= o) incl += t;
  }
  if (lane==63) wsum[wv] = incl;
  __syncthreads();
  u32 base = 0;
  for (int w=0; w<wv; ++w) base += wsum[w];
  u32 excl = base + incl - sum;
  off[b_hi] = excl;
  off[b_lo] = excl + h_hi;
}

// ---------------- zero: contiguous workspace region -----------------------
__global__ void kZero(u32* z, int nwords) {
  for (int i = blockIdx.x*256 + threadIdx.x; i < nwords; i += gridDim.x*256)
    z[i] = 0u;
}

// ---------------- A: MDN moments + hist0 — float4 (4 anchors/thread) ------
// kA floor ~46-49 us across float4/launch-bounds/float2 variants —
// structural (retired). blocks [0, ACHUNK): main; [ACHUNK,+NBLK): L1 best-gt.
__global__ __launch_bounds__(256) void kA_mdn(
    const float* __restrict__ pi, const float* __restrict__ mu,
    const float* __restrict__ sigma, float* __restrict__ logits,
    float* __restrict__ epis, float* __restrict__ alea,
    u32* __restrict__ hist0,
    const float* __restrict__ anchors, const float* __restrict__ gt,
    int* __restrict__ best) {
  __shared__ u32 s_h[2048];
  __shared__ float s_gt[NGT*4];
  __shared__ float s_ga[NGT];
  __shared__ int s_best[NGT];
  int tid = threadIdx.x;
  int img = blockIdx.y;

  if (blockIdx.x >= ACHUNK) {
    // ---------------- fused L1 body (block-uniform branch) ----------------
    int bx = blockIdx.x - ACHUNK;
    if (tid < NGT*4) s_gt[tid] = gt[img*NGT*4 + tid];
    if (tid < NGT){
      const float* g4 = gt + img*NGT*4 + tid*4;
      s_ga[tid] = (g4[2]-g4[0])*(g4[3]-g4[1]);
      s_best[tid] = 0;
    }
    __syncthreads();
    float4 an[8]; float aA[8];
#pragma unroll
    for (int q=0; q<8; ++q){
      int r = bx*256 + tid + q*(NBLK*256);
      an[q] = (r < R_ANCH) ? ((const float4*)anchors)[r]
                           : make_float4(0.f,0.f,0.f,0.f);   // IoU=0, inert
      aA[q] = (an[q].z-an[q].x)*(an[q].w-an[q].y);
    }
    float vmax[NGT];
#pragma unroll 2
    for (int g=0; g<NGT; ++g){
      float g0=s_gt[g*4], g1=s_gt[g*4+1], g2=s_gt[g*4+2], g3=s_gt[g*4+3];
      float ga=s_ga[g];
      float bi=0.0f, bu=1.0f;               // v=0 baseline
#pragma unroll
      for (int q=0; q<8; ++q){
        float lx=fmaxf(g0,an[q].x), ly=fmaxf(g1,an[q].y);
        float rx=fminf(g2,an[q].z), ry=fminf(g3,an[q].w);
        float iw=fmaxf(rx-lx,0.0f), ih=fmaxf(ry-ly,0.0f);
        float inter=iw*ih;
        float uni=fmaxf(ga+aA[q]-inter,1e-9f);
        if (inter*bu > bi*uni){ bi=inter; bu=uni; }
      }
      vmax[g] = bi/bu;
    }
    int lane = tid & 63;
#pragma unroll
    for (int g=0; g<NGT; ++g){
      float v = vmax[g];
      v = fmaxf(v, __shfl_xor(v, 1, 64));
      v = fmaxf(v, __shfl_xor(v, 2, 64));
      v = fmaxf(v, __shfl_xor(v, 4, 64));
      v = fmaxf(v, __shfl_xor(v, 8, 64));
      v = fmaxf(v, __shfl_xor(v,16, 64));
      v = fmaxf(v, __shfl_xor(v,32, 64));
      if (lane==0 && v > 0.0f) atomicMax(&s_best[g], __float_as_int(v));
    }
    __syncthreads();
    if (tid < NGT) atomicMax(&best[img*NGT + tid], s_best[tid]);
    return;
  }

  // ---------------- main MDN body: 4 anchors per thread ----------------
  int r4 = blockIdx.x*256 + tid;             // float4 index within image
  bool act = (r4 < R4);
  for (int b=tid; b<2048; b+=256) s_h[b]=0u;
  float4 lg4, ep4, al4;
  u64 keys[4];
  if (act){
    const float4* pi4 = (const float4*)pi;
    const float4* mu4 = (const float4*)mu;
    const float4* sg4 = (const float4*)sigma;
    size_t base = (size_t)img*KMIX*R4 + r4;
    float4 p4[KMIX], m4[KMIX], s4[KMIX];
#pragma unroll
    for (int k=0;k<KMIX;k++){
      p4[k]=pi4[base+(size_t)k*R4];
      m4[k]=mu4[base+(size_t)k*R4];
      s4[k]=sg4[base+(size_t)k*R4];
    }
    float lg_[4], ep_[4], al_[4];
#pragma unroll
    for (int j=0;j<4;++j){
      float p[KMIX], m[KMIX], s[KMIX];
#pragma unroll
      for (int k=0;k<KMIX;k++){
        p[k] = (&p4[k].x)[j];
        m[k] = (&m4[k].x)[j];
        s[k] = (&s4[k].x)[j];
      }
      float mx = p[0];
#pragma unroll
      for (int k=1;k<KMIX;k++) mx = fmaxf(mx,p[k]);
      float e[KMIX]; float sum = 0.0f;
#pragma unroll
      for (int k=0;k<KMIX;k++){ e[k]=expf(p[k]-mx); sum += e[k]; }
      float w[KMIX]; float lg = 0.0f;
#pragma unroll
      for (int k=0;k<KMIX;k++){ w[k]=e[k]/sum; lg += w[k]*m[k]; }
      float ep = 0.0f, al = 0.0f;
#pragma unroll
      for (int k=0;k<KMIX;k++){ float d=m[k]-lg; ep += w[k]*d*d; al += w[k]*s[k]*s[k]; }
      lg_[j]=lg; ep_[j]=ep; al_[j]=al;
      keys[j] = make_key(lg, r4*4 + j);
    }
    lg4 = make_float4(lg_[0],lg_[1],lg_[2],lg_[3]);
    ep4 = make_float4(ep_[0],ep_[1],ep_[2],ep_[3]);
    al4 = make_float4(al_[0],al_[1],al_[2],al_[3]);
    size_t o4 = (size_t)img*R4 + r4;
    ((float4*)logits)[o4] = lg4;
    ((float4*)epis)[o4]   = ep4;
    ((float4*)alea)[o4]   = al4;
  }
  __syncthreads();                           // s_h zero complete
  if (act){
#pragma unroll
    for (int j=0;j<4;++j)
      atomicAdd(&s_h[(u32)(keys[j]>>53)], 1u);
  }
  __syncthreads();
  for (int b=tid; b<2048; b+=256){ u32 v=s_h[b]; if(v) atomicAdd(&hist0[img*2048+b], v); }
}

// ---------------- P1+L2: refine hist (rare) ++ labels ride along ----------
// blocks [0, NBLK): P1 body (early-exit in common case — idle CUs);
// blocks [NBLK, NBLK+NCHUNK): kL2 label body. label is a SEPARATE buffer.
__global__ __launch_bounds__(256) void kP1L2(const float* __restrict__ logits,
    const u32* __restrict__ hist0, u32* __restrict__ hist1,
    const float* __restrict__ anchors, const float* __restrict__ gt,
    const int* __restrict__ best,
    signed char* __restrict__ label, int* __restrict__ cpos, int* __restrict__ cneg) {
  int img = blockIdx.y, tid = threadIdx.x;

  if (blockIdx.x >= NBLK) {
    // ---------------- L2 label body (verbatim kL2_label) ----------------
    __shared__ float s_gt[NGT*4];
    __shared__ float s_ga[NGT];
    __shared__ float s_bg[NGT];
    __shared__ int s_w[8];
    int bx = blockIdx.x - NBLK;
    int r = bx*256 + tid;
    if (tid < NGT*4) s_gt[tid] = gt[img*NGT*4 + tid];
    if (tid < NGT){
      const float* g4 = gt + img*NGT*4 + tid*4;
      s_ga[tid] = (g4[2]-g4[0])*(g4[3]-g4[1]);
      s_bg[tid] = __int_as_float(best[img*NGT + tid]);
    }
    __syncthreads();
    float4 a = ((const float4*)anchors)[r];
    float aA = (a.z-a.x)*(a.w-a.y);
    float bi=-1.0f, bu=1.0f; bool lq = false;
#pragma unroll 4
    for (int g=0; g<NGT; ++g){
      float g0=s_gt[g*4], g1=s_gt[g*4+1], g2=s_gt[g*4+2], g3=s_gt[g*4+3];
      float lx=fmaxf(g0,a.x), ly=fmaxf(g1,a.y);
      float rx=fminf(g2,a.z), ry=fminf(g3,a.w);
      float iw=fmaxf(rx-lx,0.0f), ih=fmaxf(ry-ly,0.0f);
      float inter=iw*ih;
      float uni = fmaxf(s_ga[g] + aA - inter, 1e-9f);
      if (inter*bu > bi*uni){ bi=inter; bu=uni; }
      float bg = s_bg[g];
      lq = lq || ((inter >= (bg - 1e-7f)*uni) && (bg > 0.0f));
    }
    float vbest = bi/bu;
    int lab = lq ? 1 : (vbest >= 0.7f ? 1 : (vbest >= 0.3f ? -1 : 0));
    label[(size_t)img*R_ANCH + r] = (signed char)lab;
    u64 bp = __ballot(lab==1), bn = __ballot(lab==0);
    int wid = tid>>6, lane = tid&63;
    if (lane==0){ s_w[wid*2]=__popcll(bp); s_w[wid*2+1]=__popcll(bn); }
    __syncthreads();
    if (tid==0){
      cpos[img*NCHUNK + bx] = s_w[0]+s_w[2]+s_w[4]+s_w[6];
      cneg[img*NCHUNK + bx] = s_w[1]+s_w[3]+s_w[5]+s_w[7];
    }
    return;
  }

  // ---------------- P1 body (verbatim) ----------------
  __shared__ u32 s_h[2048];
  __shared__ int s_i[8]; __shared__ u32 s_u[3];
  int d0,k0; u32 c0;
  pick2048(hist0 + img*2048, PRE, s_i, s_u, d0,k0,c0);
  if (c0 <= CAP_BIN) return;                 // block-uniform (common case)
  for (int b=tid; b<2048; b+=256) s_h[b]=0u;
  __syncthreads();
  const float* sc = logits + (size_t)img*R_ANCH;
  for (int r = blockIdx.x*256 + tid; r < R_ANCH; r += NBLK*256){
    u64 key = make_key(sc[r], r);
    if ((int)(key>>53) == d0) atomicAdd(&s_h[(u32)(key>>42)&2047u], 1u);
  }
  __syncthreads();
  for (int b=tid; b<2048; b+=256){ u32 v=s_h[b]; if(v) atomicAdd(&hist1[img*2048+b], v); }
}

// ---------------- G+L4: gather candidates ++ loss accumulation ------------
// R19: kP2 dispatch removed — the (essentially never taken) level-2
// refinement is built INLINE per gather block in LDS (s_h2), same counts
// as the old global hist2, same trigger (c1 > CAP_BIN).
// blocks [0, NBLK): gather body; [NBLK, NBLK+NCHUNK): kL4 body.
__global__ __launch_bounds__(256) void kGatherL4(const float* __restrict__ logits,
    const u32* __restrict__ hist0, const u32* __restrict__ hist1,
    u64* __restrict__ cand, u32* __restrict__ gcnt,
    const signed char* __restrict__ label,
    const float* __restrict__ pi, const float* __restrict__ mu,
    const float* __restrict__ sigma, const float* __restrict__ anchors,
    const float* __restrict__ gt, const float* __restrict__ deltas,
    const int* __restrict__ cpos, const int* __restrict__ cneg,
    float* __restrict__ acc) {
  int img = blockIdx.y, tid = threadIdx.x;

  if (blockIdx.x >= NBLK) {
    // ---------------- L4 body (verbatim kL4_accum) ----------------
    __shared__ int s_wp[4], s_wn[4];
    __shared__ int s_r[12];
    __shared__ float s_red[8];
    __shared__ float s_gt[NGT*4];
    int bx = blockIdx.x - NBLK;
    int lane = tid & 63, wid = tid >> 6;
    if (tid < NGT*4) s_gt[tid] = gt[img*NGT*4 + tid];
    int vp=0, vn=0, tp=0;
    for (int k=tid; k<NCHUNK; k+=256){
      int cp = cpos[img*NCHUNK + k];
      int cn = cneg[img*NCHUNK + k];
      tp += cp;
      if (k < bx){ vp += cp; vn += cn; }
    }
    for (int of=32; of>0; of>>=1){
      vp += __shfl_down(vp, of, 64);
      vn += __shfl_down(vn, of, 64);
      tp += __shfl_down(tp, of, 64);
    }
    if (lane==0){ s_r[wid]=vp; s_r[4+wid]=vn; s_r[8+wid]=tp; }
    __syncthreads();                         // also covers s_gt
    int pre_p = s_r[0]+s_r[1]+s_r[2]+s_r[3];
    int pre_n = s_r[4]+s_r[5]+s_r[6]+s_r[7];
    int totp  = s_r[8]+s_r[9]+s_r[10]+s_r[11];
    int np = totp < 128 ? totp : 128;
    int nn = 256 - np;
    int r = bx*256 + tid;
    size_t o = (size_t)img*R_ANCH + r;
    int lab = label[o];
    bool pos = (lab==1), neg = (lab==0);
    u64 bp = __ballot(pos), bn = __ballot(neg);
    if (lane==0){ s_wp[wid]=__popcll(bp); s_wn[wid]=__popcll(bn); }
    __syncthreads();
    for (int w=0; w<wid; ++w){ pre_p += s_wp[w]; pre_n += s_wn[w]; }
    u64 lm = (1ull<<lane) - 1ull;
    pre_p += __popcll(bp & lm);
    pre_n += __popcll(bn & lm);
    bool kp = pos && (pre_p < np);
    bool kn = neg && (pre_n < nn);
    float c_cls = 0.0f, c_loc = 0.0f;
    if (kp || kn){
      float4 a = ((const float4*)anchors)[r];
      float aA = (a.z-a.x)*(a.w-a.y);
      float bi = -1.0f, bu = 1.0f; int idx = 0;
#pragma unroll 4
      for (int g=0; g<NGT; ++g){
        float g0=s_gt[g*4], g1=s_gt[g*4+1], g2=s_gt[g*4+2], g3=s_gt[g*4+3];
        float ga=(g2-g0)*(g3-g1);
        float lx=fmaxf(g0,a.x), ly=fmaxf(g1,a.y);
        float rx=fminf(g2,a.z), ry=fminf(g3,a.w);
        float iw=fmaxf(rx-lx,0.0f), ih=fmaxf(ry-ly,0.0f);
        float inter=iw*ih;
        float uni = fmaxf(ga + aA - inter, 1e-9f);
        if (inter*bu > bi*uni){ bi=inter; bu=uni; idx=g; }
      }
      float vbest = bi/bu;
      size_t base = (size_t)img*KMIX*R_ANCH + r;
      float p[KMIX], m[KMIX], s[KMIX];
#pragma unroll
      for (int k=0;k<KMIX;k++){
        p[k]=pi[base+(size_t)k*R_ANCH];
        m[k]=mu[base+(size_t)k*R_ANCH];
        s[k]=sigma[base+(size_t)k*R_ANCH];
      }
      float mx = p[0];
#pragma unroll
      for (int k=1;k<KMIX;k++) mx = fmaxf(mx,p[k]);
      float e[KMIX]; float sum = 0.0f;
#pragma unroll
      for (int k=0;k<KMIX;k++){ e[k]=expf(p[k]-mx); sum += e[k]; }
      float lsum = logf(sum);
      float t_ = fminf(fmaxf(vbest, 0.0f), 1.0f);
      float comp[KMIX];
#pragma unroll
      for (int k=0;k<KMIX;k++){
        float z = (t_ - m[k]) / s[k];
        comp[k] = (p[k]-mx-lsum) - 0.5f*z*z - logf(s[k]) - HALF_L2PI;
      }
      float cm = comp[0];
#pragma unroll
      for (int k=1;k<KMIX;k++) cm = fmaxf(cm, comp[k]);
      float se = 0.0f;
#pragma unroll
      for (int k=0;k<KMIX;k++) se += expf(comp[k]-cm);
      c_cls = -(cm + logf(se));
      if (kp){
        const float* gb = &s_gt[idx*4];
        float sw = a.z-a.x, sh = a.w-a.y;
        float scx = a.x+0.5f*sw, scy = a.y+0.5f*sh;
        float tw = gb[2]-gb[0], th = gb[3]-gb[1];
        float tcx = gb[0]+0.5f*tw, tcy = gb[1]+0.5f*th;
        float4 d = ((const float4*)deltas)[(size_t)img*R_ANCH + r];
        c_loc = fabsf(d.x-(tcx-scx)/sw) + fabsf(d.y-(tcy-scy)/sh)
              + fabsf(d.z-logf(tw/sw)) + fabsf(d.w-logf(th/sh));
      }
    }
    for (int of=32; of>0; of>>=1){
      c_cls += __shfl_down(c_cls, of, 64);
      c_loc += __shfl_down(c_loc, of, 64);
    }
    if (lane==0){ s_red[wid]=c_cls; s_red[4+wid]=c_loc; }
    __syncthreads();
    if (tid==0){
      float a = s_red[0]+s_red[1]+s_red[2]+s_red[3];
      float b = s_red[4]+s_red[5]+s_red[6]+s_red[7];
      if (a != 0.0f) atomicAdd(&acc[0], a);
      if (b != 0.0f) atomicAdd(&acc[1], b);
    }
    return;
  }

  // ---------------- gather body (kGather + inline lvl-2 refine) ----------
  __shared__ int s_i[8]; __shared__ u32 s_u[3];
  __shared__ u64 s_cand[2048];               // 16 KB staging (block take <= 2048)
  __shared__ u32 s_h2[2048];                 // 8 KB inline lvl-2 hist (rare path)
  __shared__ u32 s_cnt, s_base;
  if (tid==0) s_cnt = 0u;
  int d,kk; u32 c;
  pick2048(hist0 + img*2048, PRE, s_i, s_u, d,kk,c);   // has syncthreads
  u64 p = (u64)d; int L = 0;
  const float* sc = logits + (size_t)img*R_ANCH;
  if (c > CAP_BIN){
    pick2048(hist1 + img*2048, kk, s_i, s_u, d,kk,c);
    p = (p<<11)|(u64)d; L = 1;
    if (c > CAP_BIN){
      // inline lvl-2 hist: same counts as old global hist2, built locally
      for (int b=tid; b<2048; b+=256) s_h2[b] = 0u;
      __syncthreads();
      for (int r = tid; r < R_ANCH; r += 256){
        u64 key = make_key(sc[r], r);
        if ((key>>42) == p) atomicAdd(&s_h2[(u32)(key>>31)&2047u], 1u);
      }
      __syncthreads();
      pick2048(s_h2, kk, s_i, s_u, d,kk,c);
      p = (p<<11)|(u64)d; L = 2;
    }
  }
  u64 T = p << (64 - 11*(L+1));              // total candidates <= 8143
  int lane = tid & 63;
  for (int r = blockIdx.x*256 + tid; r < R_ANCH; r += NBLK*256){
    u64 key = make_key(sc[r], r);
    bool take = (key >= T);
    u64 b = __ballot(take);
    if (b){
      u32 base = 0;
      if (lane==0) base = atomicAdd(&s_cnt, (u32)__popcll(b));   // LDS atomic
      base = (u32)__shfl((int)base, 0, 64);
      if (take){
        u32 pos = base + (u32)__popcll(b & ((1ull<<lane)-1ull));
        if (pos < 2048u) s_cand[pos] = key;
        else {                               // correctness net (block take > 2048)
          u32 gp = atomicAdd(&gcnt[img*GC_STRIDE], 1u);
          if (gp < CAND_CAP) cand[(size_t)img*CAND_CAP + gp] = key;
        }
      }
    }
  }
  __syncthreads();
  u32 n = s_cnt < 2048u ? s_cnt : 2048u;
  if (tid==0) s_base = atomicAdd(&gcnt[img*GC_STRIDE], n);  // 1 atomic/block
  __syncthreads();
  u32 gb = s_base;
  for (u32 i=tid; i<n; i+=256)
    cand[(size_t)img*CAND_CAP + gb + i] = s_cand[i];
}

// ---------------- cooperative RDE: kRank -> kD -> kEF (2 grid syncs) ------
// LDS union: rank 131.3KB / dmask 1KB / ef 74.2KB -> 131.3KB, 1 block/CU,
// grid 256 = #CUs (co-resident by construction). Phase bodies verbatim.
struct RankS {
  u64 s_key[CAND_CAP];
  u16 s_idx0[CAND_CAP];
  u16 s_idx1[CAND_CAP];
  u32 s_h0[2048];
  u32 s_off0[2048];
  u32 s_h1[2048];
  u32 s_off1[2048];
  u32 s_wsum[16];
  u32 s_nbig;
  u16 s_big[128];
};
struct DmaskS { float4 s_tile[64]; };
struct EfS {
  u64 s_list64[2048*SCAP/4];
  u16 s_cnt[2048];
  u8  kbuf[2][2048];
  u64 s_kw[32];
  int s_change, s_ovf;
  int s_wk[16], s_wn[16];
  int s_kc, s_runk, s_runn;
};

__global__ __launch_bounds__(1024) void kRDE(
    const u64* __restrict__ cand, const u32* __restrict__ gcnt,
    const float* __restrict__ epis, const float* __restrict__ alea,
    const float* __restrict__ deltas, const float* __restrict__ anchors,
    float* __restrict__ tb, float* __restrict__ tu, float* __restrict__ ts,
    u64* __restrict__ maskLT, u32* __restrict__ scnt, u16* __restrict__ slist,
    const float* __restrict__ acc, float* __restrict__ out) {
  __shared__ union { RankS r; DmaskS d; EfS e; } sm;
  cg::grid_group grid = cg::this_grid();
  int tid = threadIdx.x;
  int gblk = blockIdx.x;

  { // ================= Phase R: kRank (part, img) =================
    int part = gblk & (RPART-1), img = gblk / RPART;
    u32 cnt = gcnt[img*GC_STRIDE];
    if (cnt > (u32)CAND_CAP) cnt = CAND_CAP;
    const u64* cp = cand + (size_t)img*CAND_CAP;
    for (int i=tid; i<CAND_CAP; i+=1024) sm.r.s_key[i] = (i < (int)cnt) ? cp[i] : 0ull;
    for (int b=tid; b<2048; b+=1024){ sm.r.s_h0[b] = 0u; }
    if (tid==0) sm.r.s_nbig = 0u;
    __syncthreads();
    for (int i=tid; i<(int)cnt; i+=1024)
      atomicAdd(&sm.r.s_h0[(u32)(sm.r.s_key[i]>>53)], 1u);
    __syncthreads();
    scan2048_desc(sm.r.s_h0, sm.r.s_off0, sm.r.s_wsum, tid);
    __syncthreads();
    for (int b=tid; b<2048; b+=1024){
      u32 sz = sm.r.s_h0[b];
      if (sz > BIG_TH && sm.r.s_off0[b] < PRE && (b % RPART) == part){
        u32 q = atomicAdd(&sm.r.s_nbig, 1u);
        if (q < 128u) sm.r.s_big[q] = (u16)b;
      }
    }
    __syncthreads();                         // collect/scatter ordering
    for (int i=tid; i<(int)cnt; i+=1024){
      u32 d = (u32)(sm.r.s_key[i]>>53);
      u32 slot = atomicAdd(&sm.r.s_off0[d], 1u);
      sm.r.s_idx0[slot] = (u16)i;
    }
    __syncthreads();
    auto emit = [&](u64 my, u32 rank){
      if (rank < PRE){
        int p = (int)rank;
        u32 idx = 0xFFFFFFFFu - (u32)(my & 0xFFFFFFFFull);
        ts[img*PRE + p] = dec_score(my);
        float4 a = ((const float4*)anchors)[idx];
        float4 dd = ((const float4*)deltas)[(size_t)img*R_ANCH + idx];
        float w = a.z - a.x, h = a.w - a.y;
        float cx = a.x + 0.5f*w, cy = a.y + 0.5f*h;
        float dw = fminf(dd.z, SCALE_CLAMP_F), dh = fminf(dd.w, SCALE_CLAMP_F);
        float pcx = dd.x*w + cx, pcy = dd.y*h + cy;
        float pw = expf(dw)*w, ph = expf(dh)*h;
        float x0 = fminf(fmaxf(pcx - 0.5f*pw, 0.0f), IMG_SZ);
        float y0 = fminf(fmaxf(pcy - 0.5f*ph, 0.0f), IMG_SZ);
        float x1 = fminf(fmaxf(pcx + 0.5f*pw, 0.0f), IMG_SZ);
        float y1 = fminf(fmaxf(pcy + 0.5f*ph, 0.0f), IMG_SZ);
        ((float4*)tb)[(size_t)img*PRE + p] = make_float4(x0,y0,x1,y1);
        size_t o = (size_t)img*R_ANCH + idx;
        ((float2*)tu)[(size_t)img*PRE + p] = make_float2(epis[o], alea[o]);
      }
    };
    {
      int lo = (int)(((long long)cnt * part) / RPART);
      int hi = (int)(((long long)cnt * (part+1)) / RPART);
      for (int i=lo+tid; i<hi; i+=1024){
        u64 my = sm.r.s_key[i];
        u32 d = (u32)(my>>53);
        u32 size = sm.r.s_h0[d];
        if (size > BIG_TH) continue;
        u32 bs = sm.r.s_off0[d] - size;
        if (bs >= PRE) continue;
        u32 rank = bs;
        for (u32 q=bs; q<bs+size; ++q)
          rank += (sm.r.s_key[sm.r.s_idx0[q]] > my) ? 1u : 0u;
        emit(my, rank);
      }
    }
    __syncthreads();
    u32 nbig = sm.r.s_nbig < 128u ? sm.r.s_nbig : 128u;
    for (u32 bb=0; bb<nbig; ++bb){
      u32 B = sm.r.s_big[bb];
      u32 size = sm.r.s_h0[B];
      u32 base0 = sm.r.s_off0[B] - size;
      for (int b=tid; b<2048; b+=1024) sm.r.s_h1[b] = 0u;
      __syncthreads();
      for (u32 q=tid; q<size; q+=1024){
        u64 k = sm.r.s_key[sm.r.s_idx0[base0+q]];
        atomicAdd(&sm.r.s_h1[(u32)(k>>42)&2047u], 1u);
      }
      __syncthreads();
      scan2048_desc(sm.r.s_h1, sm.r.s_off1, sm.r.s_wsum, tid);
      __syncthreads();
      for (u32 q=tid; q<size; q+=1024){
        u16 ci = sm.r.s_idx0[base0+q];
        u64 k = sm.r.s_key[ci];
        u32 slot = atomicAdd(&sm.r.s_off1[(u32)(k>>42)&2047u], 1u);
        sm.r.s_idx1[slot] = ci;
      }
      __syncthreads();
      for (u32 q=tid; q<size; q+=1024){
        u16 ci = sm.r.s_idx1[q];
        u64 my = sm.r.s_key[ci];
        u32 d1 = (u32)(my>>42)&2047u;
        u32 ssz = sm.r.s_h1[d1];
        u32 sbs = sm.r.s_off1[d1] - ssz;
        u32 rank = base0 + sbs;
        for (u32 t2=sbs; t2<sbs+ssz; ++t2)
          rank += (sm.r.s_key[sm.r.s_idx1[t2]] > my) ? 1u : 0u;
        emit(my, rank);
      }
      __syncthreads();
    }
  }
  grid.sync();                               // tb complete for all images

  { // ================= Phase D: kD_mask (a, img) =================
    int a = gblk & 31, img = gblk >> 5;
    const float4* tbi = (const float4*)tb + (size_t)img*PRE;
    if (tid < 64){
      int i = a*64 + tid;
      sm.d.s_tile[tid] = (i < PRE) ? tbi[i] : make_float4(0.f,0.f,0.f,0.f);
    }
    __syncthreads();
    u64* outp = maskLT + ((size_t)img*32 + a)*MROW;
    u32* cnts = scnt + (size_t)img*2048;
    u16* lst  = slist + (size_t)img*2048*SCAP;
    int bmax = min(64, PRE - a*64);
    for (int j = a*64 + tid; j < MROW; j += 1024){
      u64 m = 0ull;
      if (j < PRE){
        float4 B = tbi[j];
        int blim = min(bmax, j - a*64);
        for (int b = 0; b < blim; ++b){
          float4 A = sm.d.s_tile[b];
          float v = iou_pair(A.x,A.y,A.z,A.w, B.x,B.y,B.z,B.w);
          m |= (u64)(v > NMS_T) << b;
        }
      }
      outp[j] = m;
      u64 mm = m;
      while (mm){
        int b = __builtin_ctzll(mm); mm &= mm - 1ull;
        u32 slot = atomicAdd(&cnts[j], 1u);
        if (slot < SCAP) lst[(size_t)j*SCAP + slot] = (u16)(a*64 + b);
      }
    }
  }
  grid.sync();                               // masks/lists complete

  // ================= Phase E: kEF_nms (blocks 0..NIMG-1) =================
  if (gblk >= NIMG) return;
  {
    int img = gblk;
    int lane = tid & 63, wid = tid >> 6;
    const u64* gl = (const u64*)(slist + (size_t)img*2048*SCAP);
    for (int i=tid; i<2048*SCAP/4; i+=1024) sm.e.s_list64[i] = gl[i];
    const u32* gc = scnt + (size_t)img*2048;
    for (int i=tid; i<2048; i+=1024) sm.e.s_cnt[i] = (u16)gc[i];
    if (tid==0){ sm.e.s_change = 0; sm.e.s_ovf = 0; }
    __syncthreads();
    bool myovf = false;
#pragma unroll
    for (int q=0; q<2; ++q){
      int j = tid + q*1024;
      if (sm.e.s_cnt[j] > SCAP) myovf = true;
      sm.e.kbuf[0][j] = (j < PRE) ? 1 : 0;
    }
    if (myovf) sm.e.s_ovf = 1;               // benign race
    __syncthreads();
    const u64* MT = maskLT + (size_t)img*32*MROW;
    int cur = 0;
    for (int iter=0; iter<2048; ++iter){
      bool ovf = (sm.e.s_ovf != 0);
      if (ovf && tid < 32){
        u64 w = 0ull;
        for (int b=0; b<64; ++b) w |= (u64)(sm.e.kbuf[cur][tid*64+b] & 1) << b;
        sm.e.s_kw[tid] = w;
      }
      __syncthreads();                       // A
      bool changed = false;
#pragma unroll
      for (int q=0; q<2; ++q){
        int j = tid + q*1024;
        u8 old = sm.e.kbuf[cur][j];
        u8 nk = (j < PRE) ? 1 : 0;
        if (nk){
          int cnt = sm.e.s_cnt[j];
          if (cnt <= SCAP){
            const u16* lp = (const u16*)&sm.e.s_list64[j*(SCAP/4)];
            for (int i=0; i<cnt; ++i){
              if (sm.e.kbuf[cur][lp[i]]){ nk = 0; break; }
            }
          } else {
            int amax = j >> 6;
            for (int a=0; a<=amax; ++a){
              if (MT[(size_t)a*MROW + j] & sm.e.s_kw[a]){ nk = 0; break; }
            }
          }
        }
        sm.e.kbuf[1-cur][j] = nk;
        changed |= (nk != old);
      }
      if (changed) sm.e.s_change = 1;
      __syncthreads();                       // B
      int ch = sm.e.s_change;
      __syncthreads();                       // C
      if (tid==0) sm.e.s_change = 0;
      if (!ch) break;
      cur ^= 1;
    }
    // ---- compaction, keep bits live in kbuf[cur] ----
    __syncthreads();
    const float4* tbi = (const float4*)tb + (size_t)img*PRE;
    const float NEG_INF = __uint_as_float(0xff800000u);
    u8* kf = sm.e.kbuf[1-cur];
#pragma unroll
    for (int cch=0; cch<2; ++cch){
      int pp = cch*1024 + tid;
      bool kp = false;
      if (pp < PRE && sm.e.kbuf[cur][pp]){
        float4 b = tbi[pp];
        kp = (b.z > b.x) && (b.w > b.y);
      }
      kf[pp] = kp ? 1 : 0;
    }
    __syncthreads();
    {
      int cc = (int)kf[tid] + (int)kf[1024 + tid];
      for (int of=32; of>0; of>>=1) cc += __shfl_down(cc, of, 64);
      if (lane==0) sm.e.s_wk[wid] = cc;
    }
    __syncthreads();
    if (tid==0){
      int t=0; for (int w=0; w<16; ++w) t += sm.e.s_wk[w];
      sm.e.s_kc = t; sm.e.s_runk = 0; sm.e.s_runn = 0;
    }
    __syncthreads();
    int kc = sm.e.s_kc;
#pragma unroll
    for (int cch=0; cch<2; ++cch){
      int pp = cch*1024 + tid;
      bool kp = kf[pp] != 0;
      u64 bk = __ballot(kp), bn = __ballot(!kp);
      if (lane==0){ sm.e.s_wk[wid]=__popcll(bk); sm.e.s_wn[wid]=__popcll(bn); }
      __syncthreads();
      int pk = sm.e.s_runk, pn = sm.e.s_runn;
      for (int w=0; w<wid; ++w){ pk += sm.e.s_wk[w]; pn += sm.e.s_wn[w]; }
      u64 lm = (1ull<<lane) - 1ull;
      pk += __popcll(bk & lm);
      pn += __popcll(bn & lm);
      int slot = kp ? pk : (kc + pn);
      if (slot < POST && pp < PRE){
        ((float4*)out)[img*POST + slot] = tbi[pp];
        out[32000 + img*POST + slot] = kp ? ts[img*PRE + pp] : NEG_INF;
        ((float2*)(out + 40000))[img*POST + slot] = ((const float2*)tu)[(size_t)img*PRE + pp];
      }
      __syncthreads();
      if (tid==0){
        int tk=0, tn=0;
        for (int w=0; w<16; ++w){ tk += sm.e.s_wk[w]; tn += sm.e.s_wn[w]; }
        sm.e.s_runk += tk; sm.e.s_runn += tn;
      }
      __syncthreads();
    }
    if (img==0 && tid<2) out[56000+tid] = acc[tid] * (1.0f/2048.0f);
  }
}

// ---------------- host-side launch ----------------------------------------
extern "C" void kernel_launch(void* const* d_in, const int* in_sizes, int n_in,
                              void* d_out, int out_size, void* d_ws, size_t ws_size,
                              hipStream_t stream) {
  const float* anchors = (const float*)d_in[0];
  const float* pi      = (const float*)d_in[1];
  const float* mu      = (const float*)d_in[2];
  const float* sigma   = (const float*)d_in[3];
  const float* deltas  = (const float*)d_in[4];
  const float* gt      = (const float*)d_in[5];
  float* out = (float*)d_out;

  char* ws = (char*)d_ws;
  size_t off = 0;
  auto alloc = [&](size_t bytes) -> void* {
    void* p = (void*)(ws + off);
    off += (bytes + 255) & ~(size_t)255;
    return p;
  };
  float* logits = (float*)alloc((size_t)NIMG*R_ANCH*4);
  float* epis   = (float*)alloc((size_t)NIMG*R_ANCH*4);
  float* alea   = (float*)alloc((size_t)NIMG*R_ANCH*4);
  signed char* label = (signed char*)alloc((size_t)NIMG*R_ANCH);  // own buffer (L2 runs early)
  float* tb     = (float*)alloc((size_t)NIMG*PRE*4*4);
  float* tu     = (float*)alloc((size_t)NIMG*PRE*2*4);
  float* ts     = (float*)alloc((size_t)NIMG*PRE*4);
  u64*   maskLT = (u64*)  alloc((size_t)NIMG*32*MROW*8);
  u16*   slist  = (u16*)  alloc((size_t)NIMG*2048*SCAP*2);
  u64*   cand   = (u64*)  alloc((size_t)NIMG*CAND_CAP*8);
  int*   cpos   = (int*)  alloc((size_t)NIMG*NCHUNK*4);
  int*   cneg   = (int*)  alloc((size_t)NIMG*NCHUNK*4);
  // ---- contiguous zero region ----
  size_t zstart = off;
  u32*   hist0  = (u32*)  alloc((size_t)NIMG*2048*4);
  u32*   hist1  = (u32*)  alloc((size_t)NIMG*2048*4);
  u32*   gcnt   = (u32*)  alloc((size_t)NIMG*GC_STRIDE*4);
  int*   best   = (int*)  alloc((size_t)NIMG*NGT*4);
  u32*   scnt   = (u32*)  alloc((size_t)NIMG*2048*4);
  float* acc    = (float*)alloc(8);
  int zwords = (int)((off - zstart) / 4);

  kZero<<<dim3(64), dim3(256), 0, stream>>>((u32*)(ws + zstart), zwords);
  kA_mdn<<<dim3(ACHUNK+NBLK, NIMG), dim3(256), 0, stream>>>(pi, mu, sigma, logits, epis, alea,
                                                            hist0, anchors, gt, best);
  kP1L2<<<dim3(NBLK+NCHUNK, NIMG), dim3(256), 0, stream>>>(logits, hist0, hist1,
                                                           anchors, gt, best, label, cpos, cneg);
  kGatherL4<<<dim3(NBLK+NCHUNK, NIMG), dim3(256), 0, stream>>>(logits, hist0, hist1,
                                                               cand, gcnt, label, pi, mu, sigma,
                                                               anchors, gt, deltas, cpos, cneg, acc);
  {
    const u64* cand_c = cand; const u32* gcnt_c = gcnt;
    const float* epis_c = epis; const float* alea_c = alea;
    const float* acc_c = acc;
    void* kargs[] = {
      (void*)&cand_c, (void*)&gcnt_c, (void*)&epis_c, (void*)&alea_c,
      (void*)&deltas, (void*)&anchors, (void*)&tb, (void*)&tu, (void*)&ts,
      (void*)&maskLT, (void*)&scnt, (void*)&slist, (void*)&acc_c, (void*)&out
    };
    hipLaunchCooperativeKernel(reinterpret_cast<void*>(kRDE),
                               dim3(RPART*NIMG), dim3(1024), kargs, 0, stream);
  }
}